// Round 4
// baseline (374.803 us; speedup 1.0000x reference)
//
#include <hip/hip_runtime.h>
#include <math.h>
#include <stdint.h>

// image_batch (32,1,512,512) f32, angles (8,) f32 -> out (32,8,512,512) f32
#define N_IMG 32
#define N_ANG 8
#define H_ 512
#define W_ 512

// Output tile 32x32. Rotated source span <= 31*(|c|+|s|) <= 43.85 px/axis.
// With floor/ceil margins, 4-alignment and the derived-tap margin:
//   cols used <= 55 (pitch 56, mult of 4), rows used <= 48.
// Staged per buffer: 11 chunks x 256 words = 2816 words = 11.26 KB.
// Ping-pong pair = 22.5 KB -> 7 blocks/CU (28 waves) by LDS.
#define TX 32
#define TY 32
#define LP 56
#define NCHUNK 11
#define LWORDS (NCHUNK * 256)   // 2816

__global__ __launch_bounds__(256) void rotate_tile_kernel(
    const float* __restrict__ img,     // [N_IMG][H][W]
    const float* __restrict__ angles,  // [N_ANG] degrees
    float* __restrict__ out)           // [N_IMG][N_ANG][H][W]
{
    __shared__ float tile[2][LWORDS];

    const int bz   = blockIdx.z;
    const int k    = bz >> 1;                  // angle
    const int n0   = (bz & 1) * (N_IMG / 2);   // image half (16 images/block)
    const int tx0  = blockIdx.x * TX;
    const int ty0  = blockIdx.y * TY;
    const int tid  = threadIdx.x;
    const int wid  = tid >> 6;
    const int lane = tid & 63;

    const float rad = angles[k] * 0.017453292519943295f;
    float sa, ca;
    sincosf(rad, &sa, &ca);
    const float cx = (W_ - 1) * 0.5f;
    const float cy = (H_ - 1) * 0.5f;

    // ---- source bbox (block-uniform) from the 4 tile corners ----
    float minsx = 1e30f, maxsx = -1e30f, minsy = 1e30f, maxsy = -1e30f;
#pragma unroll
    for (int cyi = 0; cyi < 2; ++cyi) {
#pragma unroll
        for (int cxi = 0; cxi < 2; ++cxi) {
            const float xr = (float)(tx0 + cxi * (TX - 1)) - cx;
            const float yr = (float)(ty0 + cyi * (TY - 1)) - cy;
            const float sx = ca * xr - sa * yr + cx;
            const float sy = sa * xr + ca * yr + cy;
            minsx = fminf(minsx, sx); maxsx = fmaxf(maxsx, sx);
            minsy = fminf(minsy, sy); maxsy = fmaxf(maxsy, sy);
        }
    }
    const int bx0 = min(max((int)floorf(minsx) - 1, 0), W_ - 1);
    const int by0 = min(max((int)floorf(minsy) - 1, 0), H_ - 1);
    const int bx0m = (bx0 & ~3) - 4;   // mult of 4 (>= -4): chunk starts stay 4-aligned
    const int by0m = by0 - 1;

    // ---- per-lane staging source offsets (computed once, reused 16 images).
    // Flat LDS word f -> (row,col), pitch 56 (col stays mult-of-4 so a lane's
    // 16B chunk never crosses an LDS row). Global side clamped in-bounds;
    // clamped chunks only ever feed weight-0 taps (4-alignment keeps valid
    // chunks exact).
    int goff[3];
    int nst = 0;
    for (int s = wid; s < NCHUNK; s += 4) {
        const int f   = s * 256 + lane * 4;
        const int row = f / LP;
        const int col = f - row * LP;
        const int grow = min(max(by0m + row, 0), H_ - 1);
        const int gcol = min(max(bx0m + col, 0), W_ - 4);
        goff[nst++] = grow * W_ + gcol;
    }

    // ---- lane -> output-pixel mapping, chosen per angle (block-uniform):
    // lanes along x when |cos|>=|sin|, else along y -> spreads LDS banks.
    const bool modeA = fabsf(ca) >= fabsf(sa);
    const int pxg = modeA ? (tid & 7) : (tid >> 5);   // 4-px group in row
    const int py  = modeA ? (tid >> 3) : (tid & 31);  // row in tile
    const int px  = pxg * 4;

    // ---- per-pixel base LDS offset + 4 bilinear weights (image-independent)
    int   ob[4];
    float w00[4], w01[4], w10[4], w11[4];
    {
        const int   yy = ty0 + py;
        const float yr = (float)yy - cy;
#pragma unroll
        for (int j = 0; j < 4; ++j) {
            const int   xx = tx0 + px + j;
            const float xr = (float)xx - cx;
            const float sxs = ca * xr - sa * yr + cx;
            const float sys = sa * xr + ca * yr + cy;
            const float x0f = floorf(sxs), y0f = floorf(sys);
            const float wx = sxs - x0f, wy = sys - y0f;
            const int x0 = (int)x0f, y0 = (int)y0f;
            const bool vx0 = ((unsigned)x0       < (unsigned)W_);
            const bool vx1 = ((unsigned)(x0 + 1) < (unsigned)W_);
            const bool vy0 = ((unsigned)y0       < (unsigned)H_);
            const bool vy1 = ((unsigned)(y0 + 1) < (unsigned)H_);
            // valid taps are never clamped (margins guarantee range); clamps
            // only keep weight-0 taps inside the staged region.
            const int lx = min(max(x0 - bx0m, 0), 54);
            const int ly = min(max(y0 - by0m, 0), 47);
            ob[j] = ly * LP + lx;
            const float omwx = 1.0f - wx, omwy = 1.0f - wy;
            w00[j] = omwy * omwx * (float)(vy0 && vx0);
            w01[j] = omwy * wx   * (float)(vy0 && vx1);
            w10[j] = wy   * omwx * (float)(vy1 && vx0);
            w11[j] = wy   * wx   * (float)(vy1 && vx1);
        }
    }

    // ---- ping-pong pipeline: stage img n+1 (other buffer) while gathering n.
    // ONE barrier per image; the vmcnt(0) drain at each barrier lands after a
    // full image of gather+store has overlapped the staging latency.
    {
        const float* __restrict__ ib = img + (size_t)n0 * (H_ * W_);
        for (int i = 0; i < nst; ++i)
            __builtin_amdgcn_global_load_lds(
                (const __attribute__((address_space(1))) void*)(ib + goff[i]),
                (__attribute__((address_space(3))) void*)(&tile[0][(wid + i * 4) * 256]),
                16, 0, 0);
    }

    for (int i = 0; i < N_IMG / 2; ++i) {
        const int n = n0 + i;
        __syncthreads();   // staging of image i complete; prior gathers/stores done

        if (i + 1 < N_IMG / 2) {
            const float* __restrict__ ibn = img + (size_t)(n + 1) * (H_ * W_);
            float* dstbuf = tile[(i + 1) & 1];
            for (int s = 0; s < nst; ++s)
                __builtin_amdgcn_global_load_lds(
                    (const __attribute__((address_space(1))) void*)(ibn + goff[s]),
                    (__attribute__((address_space(3))) void*)(&dstbuf[(wid + s * 4) * 256]),
                    16, 0, 0);
        }

        const float* __restrict__ buf = tile[i & 1];
        float v[4];
#pragma unroll
        for (int j = 0; j < 4; ++j) {
            const float* __restrict__ b0 = &buf[ob[j]];
            // taps: (y0,x0)=b0[0], (y0,x1)=b0[1], (y1,x0)=b0[LP], (y1,x1)=b0[LP+1]
            v[j] = w00[j] * b0[0]
                 + w01[j] * b0[1]
                 + w10[j] * b0[LP]
                 + w11[j] * b0[LP + 1];
        }
        float4* dst = (float4*)(out + ((size_t)(n * N_ANG + k) * H_ + ty0 + py) * W_
                                + tx0 + px);
        *dst = make_float4(v[0], v[1], v[2], v[3]);
    }
}

extern "C" void kernel_launch(void* const* d_in, const int* in_sizes, int n_in,
                              void* d_out, int out_size, void* d_ws, size_t ws_size,
                              hipStream_t stream) {
    const float* img    = (const float*)d_in[0];
    const float* angles = (const float*)d_in[1];
    float* out          = (float*)d_out;

    dim3 block(256, 1, 1);
    dim3 grid(W_ / TX, H_ / TY, N_ANG * 2);  // 16 x 16 x 16 = 4096 blocks
    rotate_tile_kernel<<<grid, block, 0, stream>>>(img, angles, out);
}